// Round 14
// baseline (237.272 us; speedup 1.0000x reference)
//
#include <hip/hip_runtime.h>
#include <cmath>

// TensorTrainGaussian: v <- (softmax_b(W_m) * NormalPDF(x_m)) @ v, M=32 steps of
// 16x16, N=131072.
//
// Counter-verified model (r7-r13): issue-slot-bound, NOT latency-bound
// (occupancy 57%->34% at equal time, r13), NOT trans-bound (Schraudolph no-op,
// r9), NOT fixable by pinning tables (compiler parks asm-loaded v4f in AGPRs
// and pays accvgpr_read in-loop, r13). FETCH=64B/sample -> avg exit step ~16.
//
// r14 = r9 base (VGPR 28, occ 57%, simplest ~99us) + pure issue-count trims:
//  - DPP quad_perm butterfly (r13-proven): -12 DS ops + no lgkm chain/step.
//  - early-exit check every 2 steps: -~10 instrs/step, <=1 extra step cost.
//  - 2-step manual unroll, paired 8B x-loads, per-sub-step laundered bases.
// Kept: Schraudolph exp2 folded in tables (e = as_float((int)max(s',0))),
//   4-way b-split (8 waves/SIMD), provable early exit (softmax cols sum to 1,
//   pdf<=0.798 => sum(v) shrinks x0.798/step; at <5e-17 final log(lik+eps)
//   within 0.21 of ref floor, tol 0.72).

#define TT_N 131072
#define TT_M 32

typedef float v2f __attribute__((ext_vector_type(2)));
typedef float v4f __attribute__((ext_vector_type(4)));

// ws layout (floats): z[16] | P'[256] | Q'[256] | R'[32*256], tables [a*16+b]
#define WS_Z 0
#define WS_P 16
#define WS_Q (16 + 256)
#define WS_R (16 + 512)
#define TBL_FLOATS (512 + 8192)

__global__ __launch_bounds__(512) void tt_prep(const float* __restrict__ Wk0,
                                               const float* __restrict__ W,
                                               const float* __restrict__ mu,
                                               const float* __restrict__ sigma,
                                               float* __restrict__ ws) {
    const int t = threadIdx.x;
    const float LOG2E = 1.4426950408889634f;
    const float SCALE = 8388608.0f;               // 2^23
    const float BIAS  = 126.94242f;               // 127 - 0.0575812 (mean-one c)
    float* z  = ws + WS_Z;
    float* PP = ws + WS_P;
    float* QQ = ws + WS_Q;
    float* RT = ws + WS_R;

    if (t < 16) {
        float mx = -1e30f;
        for (int i = 0; i < 16; ++i) mx = fmaxf(mx, Wk0[i]);
        float se = 0.f;
        for (int i = 0; i < 16; ++i) se += __expf(Wk0[i] - mx);
        z[t] = __expf(Wk0[t] - mx) / se;
    }

    if (t < 256) {
        const int a = t >> 4, b = t & 15;     // transposed [a][b]
        float s  = sigma[b * 16 + a];
        float mm = mu[b * 16 + a];
        float c2 = 0.72134752044448f / (s * s);   // 0.5*log2(e)/sigma^2
        PP[a * 16 + b] = -c2 * SCALE;
        QQ[a * 16 + b] = 2.0f * c2 * mm * SCALE;
    }

    // one thread per (m, a): column softmax over b of W[m, b, a]
    const int m = t >> 4;
    const int a = t & 15;
    const float* Wc = W + m * 256 + a;  // stride 16 over b
    float mx = -1e30f;
    #pragma unroll
    for (int b = 0; b < 16; ++b) mx = fmaxf(mx, Wc[b * 16]);
    float se = 0.f;
    #pragma unroll
    for (int b = 0; b < 16; ++b) se += __expf(Wc[b * 16] - mx);
    float lse = __log2f(se);
    #pragma unroll
    for (int b = 0; b < 16; ++b) {
        float s     = sigma[b * 16 + a];
        float mm    = mu[b * 16 + a];
        float inv_s = 1.0f / s;
        float c2    = 0.72134752044448f / (s * s);
        float lw    = (Wc[b * 16] - mx) * LOG2E - lse;   // log2 softmax weight
        float R = lw + __log2f(inv_s * 0.3989422804014327f) - c2 * mm * mm;
        RT[m * 256 + a * 16 + b] = (R + BIAS) * SCALE;
    }
}

// DPP quad_perm cross-lane (VALU pipe, no DS): ctrl 0xB1 = xor1, 0x4E = xor2
template <int CTRL>
static __device__ __forceinline__ v2f dpp_v2f(v2f x) {
    v2f r;
    r.x = __int_as_float(
        __builtin_amdgcn_mov_dpp(__float_as_int(x.x), CTRL, 0xF, 0xF, 1));
    r.y = __int_as_float(
        __builtin_amdgcn_mov_dpp(__float_as_int(x.y), CTRL, 0xF, 0xF, 1));
    return r;
}

static __device__ __forceinline__ v2f fast_exp2_pair(v2f s) {
    s = __builtin_elementwise_max(s, (v2f){0.f, 0.f});
    v2f e;
    e.x = __int_as_float((int)s.x);
    e.y = __int_as_float((int)s.y);
    return e;
}

// One TT step: consume full v[8], produce full v[8] (DPP butterfly inside).
static __device__ __forceinline__ void tt_step(v2f* __restrict__ v, float xm,
                                               const float* __restrict__ lds,
                                               const float* __restrict__ Rm,
                                               int boff, bool hi1, bool hi2) {
    const float xq = xm * xm;
    const v2f xx  = {xm, xm};
    const v2f xx2 = {xq, xq};

    int lo = 0;
    asm volatile("" : "+v"(lo));     // launder: block LICM / cross-step hoist
    const float* Pm = lds + lo;
    const float* Qm = lds + 256 + lo;
    const float* Rb = Rm + lo;

    v2f a0, a1;
    #pragma unroll
    for (int a = 0; a < 16; ++a) {
        const float vas = (a & 1) ? v[a >> 1].y : v[a >> 1].x;
        const v2f va2 = {vas, vas};
        v4f P4 = *(const v4f*)(Pm + a * 16 + boff);
        v4f Q4 = *(const v4f*)(Qm + a * 16 + boff);
        v4f R4 = *(const v4f*)(Rb + a * 16);
        v2f t0 = __builtin_elementwise_fma(Q4.xy, xx, R4.xy);
        v2f s0 = __builtin_elementwise_fma(P4.xy, xx2, t0);
        v2f t1 = __builtin_elementwise_fma(Q4.zw, xx, R4.zw);
        v2f s1 = __builtin_elementwise_fma(P4.zw, xx2, t1);
        v2f e0 = fast_exp2_pair(s0);
        v2f e1 = fast_exp2_pair(s1);
        if (a == 0) { a0 = va2 * e0; a1 = va2 * e1; }
        else {
            a0 = __builtin_elementwise_fma(va2, e0, a0);
            a1 = __builtin_elementwise_fma(va2, e1, a1);
        }
    }

    // butterfly gather via DPP (VALU pipe): rebuild full v[8]
    v2f r0 = dpp_v2f<0xB1>(a0), r1 = dpp_v2f<0xB1>(a1);   // quad_perm xor1
    v2f u0 = hi1 ? r0 : a0;
    v2f u1 = hi1 ? r1 : a1;
    v2f u2 = hi1 ? a0 : r0;
    v2f u3 = hi1 ? a1 : r1;
    v2f w0 = dpp_v2f<0x4E>(u0), w1 = dpp_v2f<0x4E>(u1);   // quad_perm xor2
    v2f w2 = dpp_v2f<0x4E>(u2), w3 = dpp_v2f<0x4E>(u3);
    v[0] = hi2 ? w0 : u0;  v[1] = hi2 ? w1 : u1;
    v[2] = hi2 ? w2 : u2;  v[3] = hi2 ? w3 : u3;
    v[4] = hi2 ? u0 : w0;  v[5] = hi2 ? u1 : w1;
    v[6] = hi2 ? u2 : w2;  v[7] = hi2 ? u3 : w3;
}

__global__ __launch_bounds__(512) void tt_main(const float* __restrict__ X,
                                               const float* __restrict__ ws,
                                               float* __restrict__ out) {
    __shared__ float lds[TBL_FLOATS];   // P'[256] | Q'[256] | R'[8192]
    {
        const v4f* src = (const v4f*)(ws + WS_P);
        v4f* dst = (v4f*)lds;
        for (int i = threadIdx.x; i < TBL_FLOATS / 4; i += 512) dst[i] = src[i];
    }
    __syncthreads();

    const int tid  = blockIdx.x * 512 + threadIdx.x;
    const int n    = tid >> 2;          // 4 lanes per sample
    const int g    = tid & 3;           // b-group: b in [4g, 4g+4)
    const int boff = g << 2;
    const bool hi1 = (g & 1) != 0;
    const bool hi2 = (g & 2) != 0;

    const float* zp = ws + WS_Z;
    v2f v[8];                            // full v over b: v[p] = {v2p, v2p+1}
    #pragma unroll
    for (int p = 0; p < 8; ++p) v[p] = (v2f){zp[2 * p], zp[2 * p + 1]};

    const float* xp = X + (size_t)n * TT_M;
    const float* ldsR = lds + 512;
    float S = 1.f;
    v2f xP = *(const v2f*)xp;            // x for steps {0,1}

    #pragma unroll 1
    for (int mo = 0; mo < 16; ++mo) {
        const v2f xC = xP;
        const int nx = (2 * mo + 2 < TT_M) ? 2 * mo + 2 : TT_M - 2;
        xP = *(const v2f*)(xp + nx);     // prefetch next pair under compute

        tt_step(v, xC.x, lds, ldsR + (2 * mo) * 256 + boff, boff, hi1, hi2);
        tt_step(v, xC.y, lds, ldsR + (2 * mo + 1) * 256 + boff, boff, hi1, hi2);

        // early-exit check once per 2 steps (sum+cmp+branch amortized)
        v2f q0 = (v[0] + v[1]) + (v[2] + v[3]);
        v2f q1 = (v[4] + v[5]) + (v[6] + v[7]);
        v2f q  = q0 + q1;
        S = q.x + q.y;
        if (__all(S < 5e-17f)) break;
    }

    if (g == 0) out[n] = logf(S + 2.2204460492503131e-16f);
}

extern "C" void kernel_launch(void* const* d_in, const int* in_sizes, int n_in,
                              void* d_out, int out_size, void* d_ws, size_t ws_size,
                              hipStream_t stream) {
    const float* X     = (const float*)d_in[0];
    const float* Wk0   = (const float*)d_in[1];
    const float* W     = (const float*)d_in[2];
    const float* mu    = (const float*)d_in[3];
    const float* sigma = (const float*)d_in[4];
    float* out = (float*)d_out;
    float* ws  = (float*)d_ws;

    tt_prep<<<1, 512, 0, stream>>>(Wk0, W, mu, sigma, ws);
    tt_main<<<(TT_N * 4) / 512, 512, 0, stream>>>(X, ws, out);
}

// Round 15
// 85.379 us; speedup vs baseline: 2.7791x; 2.7791x over previous
//
#include <hip/hip_runtime.h>
#include <cmath>

// TensorTrainGaussian: v <- (softmax_b(W_m) * NormalPDF(x_m)) @ v, M=32 steps of
// 16x16, N=131072.
//
// Counter model (r7-r14): issue-slot-bound. Measured VALU-busy/wave-step
// (~815-1100 cyc) is ~2x the hand-counted v2f stream -> compiler SCALARIZES
// __builtin_elementwise_* on v2f (never emits v_pk_fma_f32). r6's asm failed
// only because operands were 32-bit floats (odd single regs).
//
// r15: inline-asm v_pk_fma_f32 with ALL-v2f (64-bit, even-aligned) operands.
//   - s-quadratic: 2 pk_fma per b-pair (4 evals -> 4 pk_fma per a-iter).
//   - clamp+exp2 via v_cvt_u32_f32 (saturates negatives to 0 = Schraudolph
//     underflow clamp for free); bits ARE the float.
//   - scalar v_fmac accumulate (cvt outputs are scalar; kills va broadcast).
//   Per a-iter: 3 ds_read_b128 + 12 VALU (was ~21 scalarized).
// Kept from r9/r13: LDS tables, 4-way b-split (8 waves/SIMD), laundered bases,
//   DPP quad_perm butterfly, per-step provable early exit (softmax cols sum
//   to 1, pdf<=0.798 => sum(v) shrinks x0.798/step; at <5e-17 final
//   log(lik+eps) within 0.21 of ref floor, tol 0.72). NO unroll (r14 spill).

#define TT_N 131072
#define TT_M 32

typedef float v2f __attribute__((ext_vector_type(2)));
typedef float v4f __attribute__((ext_vector_type(4)));

// ws layout (floats): z[16] | P'[256] | Q'[256] | R'[32*256], tables [a*16+b]
#define WS_Z 0
#define WS_P 16
#define WS_Q (16 + 256)
#define WS_R (16 + 512)
#define TBL_FLOATS (512 + 8192)

__global__ __launch_bounds__(512) void tt_prep(const float* __restrict__ Wk0,
                                               const float* __restrict__ W,
                                               const float* __restrict__ mu,
                                               const float* __restrict__ sigma,
                                               float* __restrict__ ws) {
    const int t = threadIdx.x;
    const float LOG2E = 1.4426950408889634f;
    const float SCALE = 8388608.0f;               // 2^23
    const float BIAS  = 126.94242f;               // 127 - 0.0575812 (mean-one c)
    float* z  = ws + WS_Z;
    float* PP = ws + WS_P;
    float* QQ = ws + WS_Q;
    float* RT = ws + WS_R;

    if (t < 16) {
        float mx = -1e30f;
        for (int i = 0; i < 16; ++i) mx = fmaxf(mx, Wk0[i]);
        float se = 0.f;
        for (int i = 0; i < 16; ++i) se += __expf(Wk0[i] - mx);
        z[t] = __expf(Wk0[t] - mx) / se;
    }

    if (t < 256) {
        const int a = t >> 4, b = t & 15;     // transposed [a][b]
        float s  = sigma[b * 16 + a];
        float mm = mu[b * 16 + a];
        float c2 = 0.72134752044448f / (s * s);   // 0.5*log2(e)/sigma^2
        PP[a * 16 + b] = -c2 * SCALE;
        QQ[a * 16 + b] = 2.0f * c2 * mm * SCALE;
    }

    // one thread per (m, a): column softmax over b of W[m, b, a]
    const int m = t >> 4;
    const int a = t & 15;
    const float* Wc = W + m * 256 + a;  // stride 16 over b
    float mx = -1e30f;
    #pragma unroll
    for (int b = 0; b < 16; ++b) mx = fmaxf(mx, Wc[b * 16]);
    float se = 0.f;
    #pragma unroll
    for (int b = 0; b < 16; ++b) se += __expf(Wc[b * 16] - mx);
    float lse = __log2f(se);
    #pragma unroll
    for (int b = 0; b < 16; ++b) {
        float s     = sigma[b * 16 + a];
        float mm    = mu[b * 16 + a];
        float inv_s = 1.0f / s;
        float c2    = 0.72134752044448f / (s * s);
        float lw    = (Wc[b * 16] - mx) * LOG2E - lse;   // log2 softmax weight
        float R = lw + __log2f(inv_s * 0.3989422804014327f) - c2 * mm * mm;
        RT[m * 256 + a * 16 + b] = (R + BIAS) * SCALE;
    }
}

// DPP quad_perm cross-lane (VALU pipe, no DS): ctrl 0xB1 = xor1, 0x4E = xor2
template <int CTRL>
static __device__ __forceinline__ v2f dpp_v2f(v2f x) {
    v2f r;
    r.x = __int_as_float(
        __builtin_amdgcn_mov_dpp(__float_as_int(x.x), CTRL, 0xF, 0xF, 1));
    r.y = __int_as_float(
        __builtin_amdgcn_mov_dpp(__float_as_int(x.y), CTRL, 0xF, 0xF, 1));
    return r;
}

// Real packed fma: all operands v2f -> even-aligned VGPR pairs (r6 fix).
static __device__ __forceinline__ v2f pk_fma(v2f a, v2f b, v2f c) {
    v2f d;
    asm("v_pk_fma_f32 %0, %1, %2, %3" : "=v"(d) : "v"(a), "v"(b), "v"(c));
    return d;
}

// Schraudolph exp2 of a prescaled value; cvt_u32 saturates s<0 -> 0 -> e=0.0f.
static __device__ __forceinline__ float cvt_exp(float s) {
    unsigned u;
    asm("v_cvt_u32_f32 %0, %1" : "=v"(u) : "v"(s));
    return __uint_as_float(u);
}

__global__ __launch_bounds__(512) void tt_main(const float* __restrict__ X,
                                               const float* __restrict__ ws,
                                               float* __restrict__ out) {
    __shared__ float lds[TBL_FLOATS];   // P'[256] | Q'[256] | R'[8192]
    {
        const v4f* src = (const v4f*)(ws + WS_P);
        v4f* dst = (v4f*)lds;
        for (int i = threadIdx.x; i < TBL_FLOATS / 4; i += 512) dst[i] = src[i];
    }
    __syncthreads();

    const int tid  = blockIdx.x * 512 + threadIdx.x;
    const int n    = tid >> 2;          // 4 lanes per sample
    const int g    = tid & 3;           // b-group: b in [4g, 4g+4)
    const int boff = g << 2;
    const bool hi1 = (g & 1) != 0;
    const bool hi2 = (g & 2) != 0;

    const float* zp = ws + WS_Z;
    v2f v[8];                            // full v over b: v[p] = {v2p, v2p+1}
    #pragma unroll
    for (int p = 0; p < 8; ++p) v[p] = (v2f){zp[2 * p], zp[2 * p + 1]};

    const float* xp = X + (size_t)n * TT_M;
    float S = 1.f;
    float xn = xp[0];

    #pragma unroll 1
    for (int m = 0; m < TT_M; ++m) {
        const float xm = xn;
        xn = xp[(m + 1 < TT_M) ? m + 1 : m];   // prefetch next x under compute
        const float xq = xm * xm;
        const v2f xx  = {xm, xm};
        const v2f xx2 = {xq, xq};

        int lo = 0;
        asm volatile("" : "+v"(lo));     // launder: block LICM / hoisting
        const float* Pm = lds + lo;
        const float* Qm = lds + 256 + lo;
        const float* Rm = lds + 512 + m * 256 + boff + lo;

        float ac0 = 0.f, ac1 = 0.f, ac2 = 0.f, ac3 = 0.f;

        #pragma unroll
        for (int a = 0; a < 16; ++a) {
            const float va = (a & 1) ? v[a >> 1].y : v[a >> 1].x;
            v4f P4 = *(const v4f*)(Pm + a * 16 + boff);
            v4f Q4 = *(const v4f*)(Qm + a * 16 + boff);
            v4f R4 = *(const v4f*)(Rm + a * 16);
            // s' = P'*x^2 + (Q'*x + R')   [prescaled by 2^23, bias folded]
            v2f s0 = pk_fma(P4.xy, xx2, pk_fma(Q4.xy, xx, R4.xy));
            v2f s1 = pk_fma(P4.zw, xx2, pk_fma(Q4.zw, xx, R4.zw));
            // exp2 via saturating cvt (negatives -> 0.0f), scalar accumulate
            ac0 = __fmaf_rn(va, cvt_exp(s0.x), ac0);
            ac1 = __fmaf_rn(va, cvt_exp(s0.y), ac1);
            ac2 = __fmaf_rn(va, cvt_exp(s1.x), ac2);
            ac3 = __fmaf_rn(va, cvt_exp(s1.y), ac3);
        }

        v2f a0 = (v2f){ac0, ac1};
        v2f a1 = (v2f){ac2, ac3};

        // butterfly gather via DPP (VALU pipe): rebuild full v[8]
        v2f r0 = dpp_v2f<0xB1>(a0), r1 = dpp_v2f<0xB1>(a1);   // quad_perm xor1
        v2f u0 = hi1 ? r0 : a0;
        v2f u1 = hi1 ? r1 : a1;
        v2f u2 = hi1 ? a0 : r0;
        v2f u3 = hi1 ? a1 : r1;
        v2f w0 = dpp_v2f<0x4E>(u0), w1 = dpp_v2f<0x4E>(u1);   // quad_perm xor2
        v2f w2 = dpp_v2f<0x4E>(u2), w3 = dpp_v2f<0x4E>(u3);
        v[0] = hi2 ? w0 : u0;  v[1] = hi2 ? w1 : u1;
        v[2] = hi2 ? w2 : u2;  v[3] = hi2 ? w3 : u3;
        v[4] = hi2 ? u0 : w0;  v[5] = hi2 ? u1 : w1;
        v[6] = hi2 ? u2 : w2;  v[7] = hi2 ? u3 : w3;

        v2f q0 = (v[0] + v[1]) + (v[2] + v[3]);
        v2f q1 = (v[4] + v[5]) + (v[6] + v[7]);
        v2f q  = q0 + q1;
        S = q.x + q.y;
        if (__all(S < 5e-17f)) break;
    }

    if (g == 0) out[n] = logf(S + 2.2204460492503131e-16f);
}

extern "C" void kernel_launch(void* const* d_in, const int* in_sizes, int n_in,
                              void* d_out, int out_size, void* d_ws, size_t ws_size,
                              hipStream_t stream) {
    const float* X     = (const float*)d_in[0];
    const float* Wk0   = (const float*)d_in[1];
    const float* W     = (const float*)d_in[2];
    const float* mu    = (const float*)d_in[3];
    const float* sigma = (const float*)d_in[4];
    float* out = (float*)d_out;
    float* ws  = (float*)d_ws;

    tt_prep<<<1, 512, 0, stream>>>(Wk0, W, mu, sigma, ws);
    tt_main<<<(TT_N * 4) / 512, 512, 0, stream>>>(X, ws, out);
}

// Round 16
// 83.007 us; speedup vs baseline: 2.8584x; 1.0286x over previous
//
#include <hip/hip_runtime.h>
#include <cmath>

// TensorTrainGaussian: v <- (softmax_b(W_m) * NormalPDF(x_m)) @ v, M=32 steps of
// 16x16, N=131072.
//
// Model (r7-r15, counter-verified): issue-bound between VALU and the DS pipe.
// r15 (real v_pk_fma_f32 via all-v2f asm + saturating-cvt exp2): 85us, VGPR 44.
// Remaining structural knob: each uniform table read serves ONE sample.
//
// r16: 2 samples/lane (v2f over samples) x 4-way b-split. Table reads
//   unchanged (3 ds_read_b128/a-iter) now serve 8 evals -> DS/eval halves.
//   Per-cell P/Q/R consumed from pair regs via op_sel HALF-BROADCASTS:
//     t = pk_fma(Q2,xx,R2)  op_sel broadcast src0,src2 from half s
//     sE = pk_fma(P2,xx2,t) op_sel broadcast src0 from half s
//   (r6 failed on operand ALIGNMENT, not the modifier; r15 proved v2f asm
//   operands allocate as legal even pairs.)
//   Scalar fmac accumulate into v2f halves (no movs). DPP butterfly as r15.
//   4096 waves = 4/SIMD.
// Kept: Schraudolph exp2 prescaled tables + cvt_u32 saturation clamp,
//   laundered LDS bases (r5/r11 LICM), per-step provable early exit
//   (softmax cols sum to 1, pdf<=0.798 => sum(v) shrinks x0.798/step; at
//   <5e-17 final log(lik+eps) within 0.21 of ref floor, tol 0.72).

#define TT_N 131072
#define TT_M 32

typedef float v2f __attribute__((ext_vector_type(2)));
typedef float v4f __attribute__((ext_vector_type(4)));

// ws layout (floats): z[16] | P'[256] | Q'[256] | R'[32*256], tables [a*16+b]
#define WS_Z 0
#define WS_P 16
#define WS_Q (16 + 256)
#define WS_R (16 + 512)
#define TBL_FLOATS (512 + 8192)

__global__ __launch_bounds__(512) void tt_prep(const float* __restrict__ Wk0,
                                               const float* __restrict__ W,
                                               const float* __restrict__ mu,
                                               const float* __restrict__ sigma,
                                               float* __restrict__ ws) {
    const int t = threadIdx.x;
    const float LOG2E = 1.4426950408889634f;
    const float SCALE = 8388608.0f;               // 2^23
    const float BIAS  = 126.94242f;               // 127 - 0.0575812 (mean-one c)
    float* z  = ws + WS_Z;
    float* PP = ws + WS_P;
    float* QQ = ws + WS_Q;
    float* RT = ws + WS_R;

    if (t < 16) {
        float mx = -1e30f;
        for (int i = 0; i < 16; ++i) mx = fmaxf(mx, Wk0[i]);
        float se = 0.f;
        for (int i = 0; i < 16; ++i) se += __expf(Wk0[i] - mx);
        z[t] = __expf(Wk0[t] - mx) / se;
    }

    if (t < 256) {
        const int a = t >> 4, b = t & 15;     // transposed [a][b]
        float s  = sigma[b * 16 + a];
        float mm = mu[b * 16 + a];
        float c2 = 0.72134752044448f / (s * s);   // 0.5*log2(e)/sigma^2
        PP[a * 16 + b] = -c2 * SCALE;
        QQ[a * 16 + b] = 2.0f * c2 * mm * SCALE;
    }

    // one thread per (m, a): column softmax over b of W[m, b, a]
    const int m = t >> 4;
    const int a = t & 15;
    const float* Wc = W + m * 256 + a;  // stride 16 over b
    float mx = -1e30f;
    #pragma unroll
    for (int b = 0; b < 16; ++b) mx = fmaxf(mx, Wc[b * 16]);
    float se = 0.f;
    #pragma unroll
    for (int b = 0; b < 16; ++b) se += __expf(Wc[b * 16] - mx);
    float lse = __log2f(se);
    #pragma unroll
    for (int b = 0; b < 16; ++b) {
        float s     = sigma[b * 16 + a];
        float mm    = mu[b * 16 + a];
        float inv_s = 1.0f / s;
        float c2    = 0.72134752044448f / (s * s);
        float lw    = (Wc[b * 16] - mx) * LOG2E - lse;   // log2 softmax weight
        float R = lw + __log2f(inv_s * 0.3989422804014327f) - c2 * mm * mm;
        RT[m * 256 + a * 16 + b] = (R + BIAS) * SCALE;
    }
}

// DPP quad_perm cross-lane (VALU pipe, no DS): ctrl 0xB1 = xor1, 0x4E = xor2
template <int CTRL>
static __device__ __forceinline__ v2f dpp_v2f(v2f x) {
    v2f r;
    r.x = __int_as_float(
        __builtin_amdgcn_mov_dpp(__float_as_int(x.x), CTRL, 0xF, 0xF, 1));
    r.y = __int_as_float(
        __builtin_amdgcn_mov_dpp(__float_as_int(x.y), CTRL, 0xF, 0xF, 1));
    return r;
}

// pk_fma with src0 AND src2 broadcast from half 0: per-cell Q,R vs sample pair
static __device__ __forceinline__ v2f pk_fma_c0(v2f a, v2f b, v2f c) {
    v2f d;
    asm("v_pk_fma_f32 %0, %1, %2, %3 op_sel:[0,0,0] op_sel_hi:[0,1,0]"
        : "=v"(d) : "v"(a), "v"(b), "v"(c));
    return d;
}
static __device__ __forceinline__ v2f pk_fma_c1(v2f a, v2f b, v2f c) {
    v2f d;
    asm("v_pk_fma_f32 %0, %1, %2, %3 op_sel:[1,0,1] op_sel_hi:[1,1,1]"
        : "=v"(d) : "v"(a), "v"(b), "v"(c));
    return d;
}
// pk_fma with src0 broadcast only (src2 = running pair)
static __device__ __forceinline__ v2f pk_fma_a0(v2f a, v2f b, v2f c) {
    v2f d;
    asm("v_pk_fma_f32 %0, %1, %2, %3 op_sel:[0,0,0] op_sel_hi:[0,1,1]"
        : "=v"(d) : "v"(a), "v"(b), "v"(c));
    return d;
}
static __device__ __forceinline__ v2f pk_fma_a1(v2f a, v2f b, v2f c) {
    v2f d;
    asm("v_pk_fma_f32 %0, %1, %2, %3 op_sel:[1,0,0] op_sel_hi:[1,1,1]"
        : "=v"(d) : "v"(a), "v"(b), "v"(c));
    return d;
}

// Schraudolph exp2 of prescaled value; cvt_u32 saturates s<0 -> 0 -> e=0.0f
static __device__ __forceinline__ float cvt_exp(float s) {
    unsigned u;
    asm("v_cvt_u32_f32 %0, %1" : "=v"(u) : "v"(s));
    return __uint_as_float(u);
}

__global__ __launch_bounds__(512) void tt_main(const float* __restrict__ X,
                                               const float* __restrict__ ws,
                                               float* __restrict__ out) {
    __shared__ float lds[TBL_FLOATS];   // P'[256] | Q'[256] | R'[8192]
    {
        const v4f* src = (const v4f*)(ws + WS_P);
        v4f* dst = (v4f*)lds;
        for (int i = threadIdx.x; i < TBL_FLOATS / 4; i += 512) dst[i] = src[i];
    }
    __syncthreads();

    const int tid  = blockIdx.x * 512 + threadIdx.x;
    const int pr   = tid >> 2;          // sample-pair index
    const int n0   = pr * 2;            // samples n0, n0+1
    const int g    = tid & 3;           // b-group: b in [4g, 4g+4)
    const int boff = g << 2;
    const bool hi1 = (g & 1) != 0;
    const bool hi2 = (g & 2) != 0;

    const float* zp = ws + WS_Z;
    v2f v[16];                           // v[a] = {v_a(sample0), v_a(sample1)}
    #pragma unroll
    for (int a = 0; a < 16; ++a) v[a] = (v2f){zp[a], zp[a]};

    const float* xp0 = X + (size_t)n0 * TT_M;
    const float* xp1 = xp0 + TT_M;
    v2f S = (v2f){1.f, 1.f};
    v2f xn = (v2f){xp0[0], xp1[0]};

    #pragma unroll 1
    for (int m = 0; m < TT_M; ++m) {
        const v2f xx = xn;
        const int mn = (m + 1 < TT_M) ? m + 1 : m;
        xn = (v2f){xp0[mn], xp1[mn]};    // prefetch next x pair under compute
        const v2f xx2 = xx * xx;

        int lo = 0;
        asm volatile("" : "+v"(lo));     // launder: block LICM / hoisting
        const float* Pm = lds + lo;
        const float* Qm = lds + 256 + lo;
        const float* Rm = lds + 512 + m * 256 + boff + lo;

        v2f acc0 = {0.f, 0.f}, acc1 = {0.f, 0.f};
        v2f acc2 = {0.f, 0.f}, acc3 = {0.f, 0.f};

        #pragma unroll
        for (int a = 0; a < 16; ++a) {
            const v2f va2 = v[a];
            v4f P4 = *(const v4f*)(Pm + a * 16 + boff);
            v4f Q4 = *(const v4f*)(Qm + a * 16 + boff);
            v4f R4 = *(const v4f*)(Rm + a * 16);
            // 4 b-cells x 2 samples; each cell's P/Q/R broadcast via op_sel
            v2f s0 = pk_fma_a0(P4.xy, xx2, pk_fma_c0(Q4.xy, xx, R4.xy)); // b0
            v2f s1 = pk_fma_a1(P4.xy, xx2, pk_fma_c1(Q4.xy, xx, R4.xy)); // b1
            v2f s2 = pk_fma_a0(P4.zw, xx2, pk_fma_c0(Q4.zw, xx, R4.zw)); // b2
            v2f s3 = pk_fma_a1(P4.zw, xx2, pk_fma_c1(Q4.zw, xx, R4.zw)); // b3
            // scalar fmac accumulate into v2f halves (no cross-reg movs)
            acc0.x = __fmaf_rn(va2.x, cvt_exp(s0.x), acc0.x);
            acc0.y = __fmaf_rn(va2.y, cvt_exp(s0.y), acc0.y);
            acc1.x = __fmaf_rn(va2.x, cvt_exp(s1.x), acc1.x);
            acc1.y = __fmaf_rn(va2.y, cvt_exp(s1.y), acc1.y);
            acc2.x = __fmaf_rn(va2.x, cvt_exp(s2.x), acc2.x);
            acc2.y = __fmaf_rn(va2.y, cvt_exp(s2.y), acc2.y);
            acc3.x = __fmaf_rn(va2.x, cvt_exp(s3.x), acc3.x);
            acc3.y = __fmaf_rn(va2.y, cvt_exp(s3.y), acc3.y);
        }

        // butterfly gather via DPP: rebuild full v[16] (v2f over samples)
        v2f r0 = dpp_v2f<0xB1>(acc0), r1 = dpp_v2f<0xB1>(acc1);
        v2f r2 = dpp_v2f<0xB1>(acc2), r3 = dpp_v2f<0xB1>(acc3);
        v2f u0 = hi1 ? r0 : acc0;  v2f u1 = hi1 ? r1 : acc1;
        v2f u2 = hi1 ? r2 : acc2;  v2f u3 = hi1 ? r3 : acc3;
        v2f u4 = hi1 ? acc0 : r0;  v2f u5 = hi1 ? acc1 : r1;
        v2f u6 = hi1 ? acc2 : r2;  v2f u7 = hi1 ? acc3 : r3;
        v2f w0 = dpp_v2f<0x4E>(u0), w1 = dpp_v2f<0x4E>(u1);
        v2f w2 = dpp_v2f<0x4E>(u2), w3 = dpp_v2f<0x4E>(u3);
        v2f w4 = dpp_v2f<0x4E>(u4), w5 = dpp_v2f<0x4E>(u5);
        v2f w6 = dpp_v2f<0x4E>(u6), w7 = dpp_v2f<0x4E>(u7);
        v[0]  = hi2 ? w0 : u0;  v[1]  = hi2 ? w1 : u1;
        v[2]  = hi2 ? w2 : u2;  v[3]  = hi2 ? w3 : u3;
        v[4]  = hi2 ? w4 : u4;  v[5]  = hi2 ? w5 : u5;
        v[6]  = hi2 ? w6 : u6;  v[7]  = hi2 ? w7 : u7;
        v[8]  = hi2 ? u0 : w0;  v[9]  = hi2 ? u1 : w1;
        v[10] = hi2 ? u2 : w2;  v[11] = hi2 ? u3 : w3;
        v[12] = hi2 ? u4 : w4;  v[13] = hi2 ? u5 : w5;
        v[14] = hi2 ? u6 : w6;  v[15] = hi2 ? u7 : w7;

        v2f q0 = (v[0] + v[1]) + (v[2] + v[3]);
        v2f q1 = (v[4] + v[5]) + (v[6] + v[7]);
        v2f q2 = (v[8] + v[9]) + (v[10] + v[11]);
        v2f q3 = (v[12] + v[13]) + (v[14] + v[15]);
        S = (q0 + q1) + (q2 + q3);
        if (__all(fmaxf(S.x, S.y) < 5e-17f)) break;
    }

    const float eps = 2.2204460492503131e-16f;
    if (g == 0) {
        out[n0]     = logf(S.x + eps);
        out[n0 + 1] = logf(S.y + eps);
    }
}

extern "C" void kernel_launch(void* const* d_in, const int* in_sizes, int n_in,
                              void* d_out, int out_size, void* d_ws, size_t ws_size,
                              hipStream_t stream) {
    const float* X     = (const float*)d_in[0];
    const float* Wk0   = (const float*)d_in[1];
    const float* W     = (const float*)d_in[2];
    const float* mu    = (const float*)d_in[3];
    const float* sigma = (const float*)d_in[4];
    float* out = (float*)d_out;
    float* ws  = (float*)d_ws;

    tt_prep<<<1, 512, 0, stream>>>(Wk0, W, mu, sigma, ws);
    tt_main<<<(TT_N / 2 * 4) / 512, 512, 0, stream>>>(X, ws, out);
}

// Round 17
// 81.775 us; speedup vs baseline: 2.9015x; 1.0151x over previous
//
#include <hip/hip_runtime.h>
#include <cmath>

// TensorTrainGaussian: v <- (softmax_b(W_m) * NormalPDF(x_m)) @ v, M=32 steps of
// 16x16, N=131072.
//
// r16 (83us): 2 samples/lane x 4-way b-split, op_sel pk_fma, Schraudolph-cvt.
// Remaining per-step overhead: full-v butterfly rebuild (24 DPP + 48 cndmask,
// serial) + v[16] (32 VGPR).
//
// r17: DEFERRED BROADCAST. Lanes keep only their 4 owned acc components;
//   next step fetches va for a=(h,j) via quad_perm[h,h,h,h] DPP broadcast
//   (ctrl h*0x55) inline in the a-loop (32 DPP/step, overlappable) -> no
//   butterfly, no v[16]. 2-step ping-pong (A->B->A), exit check every 2 steps
//   with exact sum via 2-round quad DPP-add reduce.
// Kept: op_sel pk_fma half-broadcasts (r16), saturating-cvt Schraudolph exp2
//   in prescaled tables, LDS tables + laundered bases, provable early exit
//   (softmax cols sum to 1, pdf<=0.798 => sum(v) shrinks x0.798/step; at
//   <5e-17 final log(lik+eps) within 0.21 of ref floor, tol 0.72).

#define TT_N 131072
#define TT_M 32

typedef float v2f __attribute__((ext_vector_type(2)));
typedef float v4f __attribute__((ext_vector_type(4)));

// ws layout (floats): z[16] | P'[256] | Q'[256] | R'[32*256], tables [a*16+b]
#define WS_Z 0
#define WS_P 16
#define WS_Q (16 + 256)
#define WS_R (16 + 512)
#define TBL_FLOATS (512 + 8192)

__global__ __launch_bounds__(512) void tt_prep(const float* __restrict__ Wk0,
                                               const float* __restrict__ W,
                                               const float* __restrict__ mu,
                                               const float* __restrict__ sigma,
                                               float* __restrict__ ws) {
    const int t = threadIdx.x;
    const float LOG2E = 1.4426950408889634f;
    const float SCALE = 8388608.0f;               // 2^23
    const float BIAS  = 126.94242f;               // 127 - 0.0575812 (mean-one c)
    float* z  = ws + WS_Z;
    float* PP = ws + WS_P;
    float* QQ = ws + WS_Q;
    float* RT = ws + WS_R;

    if (t < 16) {
        float mx = -1e30f;
        for (int i = 0; i < 16; ++i) mx = fmaxf(mx, Wk0[i]);
        float se = 0.f;
        for (int i = 0; i < 16; ++i) se += __expf(Wk0[i] - mx);
        z[t] = __expf(Wk0[t] - mx) / se;
    }

    if (t < 256) {
        const int a = t >> 4, b = t & 15;     // transposed [a][b]
        float s  = sigma[b * 16 + a];
        float mm = mu[b * 16 + a];
        float c2 = 0.72134752044448f / (s * s);   // 0.5*log2(e)/sigma^2
        PP[a * 16 + b] = -c2 * SCALE;
        QQ[a * 16 + b] = 2.0f * c2 * mm * SCALE;
    }

    // one thread per (m, a): column softmax over b of W[m, b, a]
    const int m = t >> 4;
    const int a = t & 15;
    const float* Wc = W + m * 256 + a;  // stride 16 over b
    float mx = -1e30f;
    #pragma unroll
    for (int b = 0; b < 16; ++b) mx = fmaxf(mx, Wc[b * 16]);
    float se = 0.f;
    #pragma unroll
    for (int b = 0; b < 16; ++b) se += __expf(Wc[b * 16] - mx);
    float lse = __log2f(se);
    #pragma unroll
    for (int b = 0; b < 16; ++b) {
        float s     = sigma[b * 16 + a];
        float mm    = mu[b * 16 + a];
        float inv_s = 1.0f / s;
        float c2    = 0.72134752044448f / (s * s);
        float lw    = (Wc[b * 16] - mx) * LOG2E - lse;   // log2 softmax weight
        float R = lw + __log2f(inv_s * 0.3989422804014327f) - c2 * mm * mm;
        RT[m * 256 + a * 16 + b] = (R + BIAS) * SCALE;
    }
}

template <int CTRL>
static __device__ __forceinline__ float dpp_f(float x) {
    return __int_as_float(
        __builtin_amdgcn_mov_dpp(__float_as_int(x), CTRL, 0xF, 0xF, 1));
}
template <int CTRL>
static __device__ __forceinline__ v2f dpp_v2f(v2f x) {
    v2f r;
    r.x = dpp_f<CTRL>(x.x);
    r.y = dpp_f<CTRL>(x.y);
    return r;
}

// op_sel pk_fma half-broadcast helpers (r16-proven)
static __device__ __forceinline__ v2f pk_fma_c0(v2f a, v2f b, v2f c) {
    v2f d;
    asm("v_pk_fma_f32 %0, %1, %2, %3 op_sel:[0,0,0] op_sel_hi:[0,1,0]"
        : "=v"(d) : "v"(a), "v"(b), "v"(c));
    return d;
}
static __device__ __forceinline__ v2f pk_fma_c1(v2f a, v2f b, v2f c) {
    v2f d;
    asm("v_pk_fma_f32 %0, %1, %2, %3 op_sel:[1,0,1] op_sel_hi:[1,1,1]"
        : "=v"(d) : "v"(a), "v"(b), "v"(c));
    return d;
}
static __device__ __forceinline__ v2f pk_fma_a0(v2f a, v2f b, v2f c) {
    v2f d;
    asm("v_pk_fma_f32 %0, %1, %2, %3 op_sel:[0,0,0] op_sel_hi:[0,1,1]"
        : "=v"(d) : "v"(a), "v"(b), "v"(c));
    return d;
}
static __device__ __forceinline__ v2f pk_fma_a1(v2f a, v2f b, v2f c) {
    v2f d;
    asm("v_pk_fma_f32 %0, %1, %2, %3 op_sel:[1,0,0] op_sel_hi:[1,1,1]"
        : "=v"(d) : "v"(a), "v"(b), "v"(c));
    return d;
}

// Schraudolph exp2 of prescaled value; cvt_u32 saturates s<0 -> 0 -> e=0.0f
static __device__ __forceinline__ float cvt_exp(float s) {
    unsigned u;
    asm("v_cvt_u32_f32 %0, %1" : "=v"(u) : "v"(s));
    return __uint_as_float(u);
}

// One a-group (4 a-iters, va fetched from quad-lane H via DPP broadcast)
template <int H>
static __device__ __forceinline__ void a_group(const v2f* __restrict__ prev,
                                               v2f& n0, v2f& n1, v2f& n2, v2f& n3,
                                               v2f xx, v2f xx2,
                                               const float* __restrict__ Pm,
                                               const float* __restrict__ Qm,
                                               const float* __restrict__ Rm,
                                               int boff) {
    #pragma unroll
    for (int j = 0; j < 4; ++j) {
        const int a = H * 4 + j;
        const v2f va2 = dpp_v2f<H * 0x55>(prev[j]);   // quad_perm [H,H,H,H]
        v4f P4 = *(const v4f*)(Pm + a * 16 + boff);
        v4f Q4 = *(const v4f*)(Qm + a * 16 + boff);
        v4f R4 = *(const v4f*)(Rm + a * 16);
        v2f s0 = pk_fma_a0(P4.xy, xx2, pk_fma_c0(Q4.xy, xx, R4.xy)); // b0
        v2f s1 = pk_fma_a1(P4.xy, xx2, pk_fma_c1(Q4.xy, xx, R4.xy)); // b1
        v2f s2 = pk_fma_a0(P4.zw, xx2, pk_fma_c0(Q4.zw, xx, R4.zw)); // b2
        v2f s3 = pk_fma_a1(P4.zw, xx2, pk_fma_c1(Q4.zw, xx, R4.zw)); // b3
        n0.x = __fmaf_rn(va2.x, cvt_exp(s0.x), n0.x);
        n0.y = __fmaf_rn(va2.y, cvt_exp(s0.y), n0.y);
        n1.x = __fmaf_rn(va2.x, cvt_exp(s1.x), n1.x);
        n1.y = __fmaf_rn(va2.y, cvt_exp(s1.y), n1.y);
        n2.x = __fmaf_rn(va2.x, cvt_exp(s2.x), n2.x);
        n2.y = __fmaf_rn(va2.y, cvt_exp(s2.y), n2.y);
        n3.x = __fmaf_rn(va2.x, cvt_exp(s3.x), n3.x);
        n3.y = __fmaf_rn(va2.y, cvt_exp(s3.y), n3.y);
    }
}

// One TT step: prev[4] (own b components) -> next[4], via quad DPP broadcasts
static __device__ __forceinline__ void tt_step(const v2f* __restrict__ prev,
                                               v2f* __restrict__ next,
                                               v2f xx,
                                               const float* __restrict__ lds,
                                               int m, int boff) {
    const v2f xx2 = xx * xx;
    int lo = 0;
    asm volatile("" : "+v"(lo));     // launder: block LICM / hoisting
    const float* Pm = lds + lo;
    const float* Qm = lds + 256 + lo;
    const float* Rm = lds + 512 + m * 256 + boff + lo;

    v2f n0 = {0.f, 0.f}, n1 = {0.f, 0.f}, n2 = {0.f, 0.f}, n3 = {0.f, 0.f};
    a_group<0>(prev, n0, n1, n2, n3, xx, xx2, Pm, Qm, Rm, boff);
    a_group<1>(prev, n0, n1, n2, n3, xx, xx2, Pm, Qm, Rm, boff);
    a_group<2>(prev, n0, n1, n2, n3, xx, xx2, Pm, Qm, Rm, boff);
    a_group<3>(prev, n0, n1, n2, n3, xx, xx2, Pm, Qm, Rm, boff);
    next[0] = n0; next[1] = n1; next[2] = n2; next[3] = n3;
}

__global__ __launch_bounds__(512) void tt_main(const float* __restrict__ X,
                                               const float* __restrict__ ws,
                                               float* __restrict__ out) {
    __shared__ float lds[TBL_FLOATS];   // P'[256] | Q'[256] | R'[8192]
    {
        const v4f* src = (const v4f*)(ws + WS_P);
        v4f* dst = (v4f*)lds;
        for (int i = threadIdx.x; i < TBL_FLOATS / 4; i += 512) dst[i] = src[i];
    }
    __syncthreads();

    const int tid  = blockIdx.x * 512 + threadIdx.x;
    const int pr   = tid >> 2;          // sample-pair index
    const int n0s  = pr * 2;            // samples n0s, n0s+1
    const int g    = tid & 3;           // b-group: own b in [4g, 4g+4)
    const int boff = g << 2;

    const float* zp = ws + WS_Z;
    v2f A[4], B[4];                      // own 4 components, over 2 samples
    #pragma unroll
    for (int j = 0; j < 4; ++j) A[j] = (v2f){zp[boff + j], zp[boff + j]};

    const float* xp0 = X + (size_t)n0s * TT_M;
    const float* xp1 = xp0 + TT_M;
    v2f S = (v2f){1.f, 1.f};
    v2f c0 = *(const v2f*)xp0;           // {x0, x1} sample0
    v2f c1 = *(const v2f*)xp1;           // {x0, x1} sample1

    #pragma unroll 1
    for (int mo = 0; mo < 16; ++mo) {
        const int nx = (2 * mo + 2 < TT_M) ? 2 * mo + 2 : TT_M - 2;
        v2f c0n = *(const v2f*)(xp0 + nx);   // prefetch next x pair
        v2f c1n = *(const v2f*)(xp1 + nx);

        const v2f xE = (v2f){c0.x, c1.x};    // even step x over samples
        const v2f xO = (v2f){c0.y, c1.y};    // odd step x

        tt_step(A, B, xE, lds, 2 * mo, boff);
        tt_step(B, A, xO, lds, 2 * mo + 1, boff);

        // exit check every 2 steps: exact sum via quad DPP-add reduce
        v2f part = (A[0] + A[1]) + (A[2] + A[3]);
        part.x += dpp_f<0xB1>(part.x);       // + xor1 neighbor
        part.y += dpp_f<0xB1>(part.y);
        part.x += dpp_f<0x4E>(part.x);       // + xor2 neighbor
        part.y += dpp_f<0x4E>(part.y);
        S = part;                             // full sum, all quad lanes
        if (__all(fmaxf(S.x, S.y) < 5e-17f)) break;

        c0 = c0n; c1 = c1n;
    }

    const float eps = 2.2204460492503131e-16f;
    if (g == 0) {
        out[n0s]     = logf(S.x + eps);
        out[n0s + 1] = logf(S.y + eps);
    }
}

extern "C" void kernel_launch(void* const* d_in, const int* in_sizes, int n_in,
                              void* d_out, int out_size, void* d_ws, size_t ws_size,
                              hipStream_t stream) {
    const float* X     = (const float*)d_in[0];
    const float* Wk0   = (const float*)d_in[1];
    const float* W     = (const float*)d_in[2];
    const float* mu    = (const float*)d_in[3];
    const float* sigma = (const float*)d_in[4];
    float* out = (float*)d_out;
    float* ws  = (float*)d_ws;

    tt_prep<<<1, 512, 0, stream>>>(Wk0, W, mu, sigma, ws);
    tt_main<<<(TT_N / 2 * 4) / 512, 512, 0, stream>>>(X, ws, out);
}